// Round 9
// baseline (128.190 us; speedup 1.0000x reference)
//
#include <hip/hip_runtime.h>
#include <hip/hip_bf16.h>
#include <math.h>

#define BB 1024
#define DD 64
#define HH 128

typedef _Float16 half8 __attribute__((ext_vector_type(8)));
typedef __fp16 fp16x2 __attribute__((ext_vector_type(2)));
typedef float floatx4 __attribute__((ext_vector_type(4)));

union H8 { fp16x2 p[4]; half8 v; };

// async global -> LDS, 16B per lane. lds base must be wave-uniform; HW adds lane*16.
__device__ __forceinline__ void async_cp16(const float* g, float* lds_wave_base) {
    __builtin_amdgcn_global_load_lds(
        (const __attribute__((address_space(1))) unsigned int*)g,
        (__attribute__((address_space(3))) unsigned int*)lds_wave_base,
        16, 0, 0);
}

// ---------------------------------------------------------------------------
// Prep v3 (4 waves/SIMD, same arithmetic):
//  grid (512, 2) x 256. Block = 2 i rows x 128 h columns (1 h per lane).
//  y==0: c1[i,h] = x_i @ (Wi+Wd) + b1
//  y==1: c2P scatter of x_j @ (Wj-Wd), + wpack (blocks 0..31)
//  c2P[(j>>4)*2048 + (h>>6)*1024 + ((h>>4)&3)*256
//      + ((j&15)>>2)*64 + (h&15)*4 + (j&3)]
//  wpack[((hh*8 + t4*2 + s)*64 + l)*8 + jj]
//      = f16( Wab[s*32 + (l>>4)*8 + jj][hh*64 + t4*16 + (l&15)] )
// ---------------------------------------------------------------------------
__global__ __launch_bounds__(256) void prep_kernel(
    const float* __restrict__ x, const float* __restrict__ W1,
    const float* __restrict__ b1,
    float* __restrict__ c1, float* __restrict__ c2P,
    _Float16* __restrict__ wpack)
{
    __shared__ float xs[2][DD];
    const int t = threadIdx.x;        // 0..255
    const int i0 = blockIdx.x * 2;
    if (t < 128) xs[t >> 6][t & 63] = x[i0 * DD + t];
    __syncthreads();

    const int ii = t >> 7;            // 0..1
    const int h = t & 127;            // h column (coalesced across lanes)
    const int i = i0 + ii;

    if (blockIdx.y == 0) {
        float a1 = 0.f;
        #pragma unroll 8
        for (int k = 0; k < DD; k++) {
            float wi = W1[k * HH + h];
            float wd = W1[(2 * DD + k) * HH + h];
            a1 = fmaf(xs[ii][k], wi + wd, a1);
        }
        c1[i * HH + h] = a1 + b1[h];
    } else {
        float a2 = 0.f;
        #pragma unroll 8
        for (int k = 0; k < DD; k++) {
            float wj = W1[(DD + k) * HH + h];
            float wd = W1[(2 * DD + k) * HH + h];
            a2 = fmaf(xs[ii][k], wj - wd, a2);
        }
        // scatter into hh-split MFMA C-fragment order (single column h)
        c2P[(i >> 4) * 2048 + (h >> 6) * 1024 + ((h >> 4) & 3) * 256
            + ((i & 15) >> 2) * 64 + (h & 15) * 4 + (i & 3)] = a2;

        if (blockIdx.x < 32) {
            int f = blockIdx.x * 256 + t;        // 0..8191
            int jj = f & 7;
            int l  = (f >> 3) & 63;
            int u  = f >> 9;                     // hh*8 + t4*2 + s
            int s  = u & 1, t4 = (u >> 1) & 3, hh = u >> 3;
            int k  = s * 32 + ((l >> 4) << 3) + jj;
            int hcol = hh * 64 + t4 * 16 + (l & 15);
            wpack[f] = (_Float16)W1[(3 * DD + k) * HH + hcol];
        }
    }
}

// ---------------------------------------------------------------------------
// Pair kernel v7: Sp[jg][i][hh*64+..] = sum_{j in EIGHTH jg}
//     relu(|x_i-x_j| @ Wab[:,h-half] + c1[i] + c2[j])
// Grid 2048 = 128 ig x 2 hh x 8 jg. Block = 4 waves x 2 i = 8 i rows.
// Change vs v6 (40us, occupancy 18.6%, all pipes <40% busy, conflicts 0):
//  v6 was latency/barrier-bound with only 4 blocks/CU of overlap (grid
//  1024). Split j 4 quarters -> 8 eighths (128 j = 8 tiles each): grid
//  2048 = up to 6 blocks/CU (VGPR-80 cap) at drifted phases, so one
//  block's compute covers another's staging drain. Per-CU totals of
//  MFMA / LDS / VALU / staging bytes unchanged; Sp doubles to 8 partials.
// Kept from v6: 2 i/wave, c2 register-held as shared MFMA C operand,
//  part-major conflict-free xs, max-fold relu (+c1 hoisted: 32 j/S-reg).
// ---------------------------------------------------------------------------
__global__ __launch_bounds__(256, 3) void pair_kernel(
    const float* __restrict__ x, const float* __restrict__ c1,
    const float* __restrict__ c2P, const _Float16* __restrict__ wpack,
    float* __restrict__ Sp)
{
    __shared__ __align__(16) float xs[2][1024];   // 2 x 4 KB part-major: [p][l][4]
    __shared__ __align__(16) float c2s[2][1024];  // 2 x 4 KB (hh-half fragment order)

    const int t = threadIdx.x;
    const int wave = t >> 6;
    const int l = t & 63;
    const int quad = l >> 4, lm = l & 15;
    const int bid = blockIdx.x;
    const int ig = bid >> 4;         // 0..127 (8 i rows per block)
    const int hh = (bid >> 3) & 1;
    const int jg = bid & 7;          // j eighth (fastest -> XCD locality)
    const int iA = ig * 8 + wave * 2;
    const int iB = iA + 1;
    const int j0base = jg * 128;
    // xs staging source: lane l of wave w supplies row (l&15),
    // k-chunk c = (l>>4)*2 + (w&1) + ((w>>1)<<3)   (4 floats at c*4)
    const int xoff = ((l >> 4) * 2 + (wave & 1) + ((wave >> 1) << 3)) << 2;

    // stage tile 0 (async)
    async_cp16(x + (j0base + lm) * DD + xoff, &xs[0][0] + wave * 256);
    async_cp16(c2P + (j0base >> 4) * 2048 + hh * 1024 + t * 4,
               &c2s[0][0] + wave * 256);

    // wave-private register data (overlaps staging)
    float xiA[16], xiB[16];
    {
        const float* xg = x + iA * DD + quad * 8;
        *(float4*)(xiA)      = *(const float4*)(xg);
        *(float4*)(xiA + 4)  = *(const float4*)(xg + 4);
        *(float4*)(xiA + 8)  = *(const float4*)(xg + 32);
        *(float4*)(xiA + 12) = *(const float4*)(xg + 36);
        const float* xh = x + iB * DD + quad * 8;
        *(float4*)(xiB)      = *(const float4*)(xh);
        *(float4*)(xiB + 4)  = *(const float4*)(xh + 4);
        *(float4*)(xiB + 8)  = *(const float4*)(xh + 32);
        *(float4*)(xiB + 12) = *(const float4*)(xh + 36);
    }
    float c1A[4], c1B[4];
    #pragma unroll
    for (int t4 = 0; t4 < 4; t4++) {
        c1A[t4] = c1[iA * HH + hh * 64 + t4 * 16 + lm];
        c1B[t4] = c1[iB * HH + hh * 64 + t4 * 16 + lm];
    }
    half8 wf[8];
    #pragma unroll
    for (int u = 0; u < 8; u++)
        wf[u] = *(const half8*)(wpack + ((hh * 8 + u) * 64 + l) * 8);

    float SA[4] = {0.f, 0.f, 0.f, 0.f};
    float SB[4] = {0.f, 0.f, 0.f, 0.f};

    for (int tile = 0; tile < 8; ++tile) {
        const int cur = tile & 1;
        __syncthreads();   // staged data for 'tile' landed; other buffer free

        if (tile < 7) {    // prefetch next tile (async)
            const int jn = j0base + (tile + 1) * 16;
            async_cp16(x + (jn + lm) * DD + xoff, &xs[cur ^ 1][0] + wave * 256);
            async_cp16(c2P + (jn >> 4) * 2048 + hh * 1024 + t * 4,
                       &c2s[cur ^ 1][0] + wave * 256);
        }

        // A data (h-independent): part-major, conflict-free linear reads
        const float* xb = &xs[cur][l * 4];
        float4 a0 = *(const float4*)(xb);
        float4 a1 = *(const float4*)(xb + 256);
        float4 a2 = *(const float4*)(xb + 512);
        float4 a3 = *(const float4*)(xb + 768);

        // c2 fragment: loaded ONCE, shared as MFMA C for both i
        floatx4 c2v[4];
        #pragma unroll
        for (int t4 = 0; t4 < 4; t4++)
            c2v[t4] = *(const floatx4*)(&c2s[cur][t4 * 256 + l * 4]);

        // build BOTH i's A-fragments while a0..a3 live (then freed)
        H8 afA0, afA1, afB0, afB1;
        afA0.p[0] = __builtin_amdgcn_cvt_pkrtz(fabsf(xiA[0] - a0.x),  fabsf(xiA[1] - a0.y));
        afA0.p[1] = __builtin_amdgcn_cvt_pkrtz(fabsf(xiA[2] - a0.z),  fabsf(xiA[3] - a0.w));
        afA0.p[2] = __builtin_amdgcn_cvt_pkrtz(fabsf(xiA[4] - a1.x),  fabsf(xiA[5] - a1.y));
        afA0.p[3] = __builtin_amdgcn_cvt_pkrtz(fabsf(xiA[6] - a1.z),  fabsf(xiA[7] - a1.w));
        afA1.p[0] = __builtin_amdgcn_cvt_pkrtz(fabsf(xiA[8] - a2.x),  fabsf(xiA[9] - a2.y));
        afA1.p[1] = __builtin_amdgcn_cvt_pkrtz(fabsf(xiA[10] - a2.z), fabsf(xiA[11] - a2.w));
        afA1.p[2] = __builtin_amdgcn_cvt_pkrtz(fabsf(xiA[12] - a3.x), fabsf(xiA[13] - a3.y));
        afA1.p[3] = __builtin_amdgcn_cvt_pkrtz(fabsf(xiA[14] - a3.z), fabsf(xiA[15] - a3.w));
        afB0.p[0] = __builtin_amdgcn_cvt_pkrtz(fabsf(xiB[0] - a0.x),  fabsf(xiB[1] - a0.y));
        afB0.p[1] = __builtin_amdgcn_cvt_pkrtz(fabsf(xiB[2] - a0.z),  fabsf(xiB[3] - a0.w));
        afB0.p[2] = __builtin_amdgcn_cvt_pkrtz(fabsf(xiB[4] - a1.x),  fabsf(xiB[5] - a1.y));
        afB0.p[3] = __builtin_amdgcn_cvt_pkrtz(fabsf(xiB[6] - a1.z),  fabsf(xiB[7] - a1.w));
        afB1.p[0] = __builtin_amdgcn_cvt_pkrtz(fabsf(xiB[8] - a2.x),  fabsf(xiB[9] - a2.y));
        afB1.p[1] = __builtin_amdgcn_cvt_pkrtz(fabsf(xiB[10] - a2.z), fabsf(xiB[11] - a2.w));
        afB1.p[2] = __builtin_amdgcn_cvt_pkrtz(fabsf(xiB[12] - a3.x), fabsf(xiB[13] - a3.y));
        afB1.p[3] = __builtin_amdgcn_cvt_pkrtz(fabsf(xiB[14] - a3.z), fabsf(xiB[15] - a3.w));

        // --- i = iA: C = c2v (kept live); relu via max(.., -c1) ---
        {
            floatx4 acc[4];
            #pragma unroll
            for (int t4 = 0; t4 < 4; t4++) {
                acc[t4] = __builtin_amdgcn_mfma_f32_16x16x32_f16(afA0.v, wf[t4 * 2 + 0], c2v[t4], 0, 0, 0);
                acc[t4] = __builtin_amdgcn_mfma_f32_16x16x32_f16(afA1.v, wf[t4 * 2 + 1], acc[t4], 0, 0, 0);
            }
            #pragma unroll
            for (int t4 = 0; t4 < 4; t4++) {
                SA[t4] += fmaxf(acc[t4][0], -c1A[t4]);
                SA[t4] += fmaxf(acc[t4][1], -c1A[t4]);
                SA[t4] += fmaxf(acc[t4][2], -c1A[t4]);
                SA[t4] += fmaxf(acc[t4][3], -c1A[t4]);
            }
        }
        // --- i = iB: SAME c2v registers as C (no LDS re-read) ---
        {
            floatx4 acc[4];
            #pragma unroll
            for (int t4 = 0; t4 < 4; t4++) {
                acc[t4] = __builtin_amdgcn_mfma_f32_16x16x32_f16(afB0.v, wf[t4 * 2 + 0], c2v[t4], 0, 0, 0);
                acc[t4] = __builtin_amdgcn_mfma_f32_16x16x32_f16(afB1.v, wf[t4 * 2 + 1], acc[t4], 0, 0, 0);
            }
            #pragma unroll
            for (int t4 = 0; t4 < 4; t4++) {
                SB[t4] += fmaxf(acc[t4][0], -c1B[t4]);
                SB[t4] += fmaxf(acc[t4][1], -c1B[t4]);
                SB[t4] += fmaxf(acc[t4][2], -c1B[t4]);
                SB[t4] += fmaxf(acc[t4][3], -c1B[t4]);
            }
        }
    }

    // hoisted +c1 term: each S reg accumulated 32 j-rows (8 tiles x 4 regs)
    #pragma unroll
    for (int t4 = 0; t4 < 4; t4++) {
        SA[t4] = fmaf(32.f, c1A[t4], SA[t4]);
        SB[t4] = fmaf(32.f, c1B[t4], SB[t4]);
    }
    // reduce across the 4 quads (same h = lm+16*t4, different j-rows)
    #pragma unroll
    for (int t4 = 0; t4 < 4; t4++) {
        SA[t4] += __shfl_xor(SA[t4], 16, 64);
        SA[t4] += __shfl_xor(SA[t4], 32, 64);
        SB[t4] += __shfl_xor(SB[t4], 16, 64);
        SB[t4] += __shfl_xor(SB[t4], 32, 64);
    }
    if (quad == 0) {
        #pragma unroll
        for (int t4 = 0; t4 < 4; t4++) {
            Sp[(jg * BB + iA) * HH + hh * 64 + t4 * 16 + lm] = SA[t4];
            Sp[(jg * BB + iB) * HH + hh * 64 + t4 * 16 + lm] = SB[t4];
        }
    }
}

// ---------------------------------------------------------------------------
// Finish v4 (2 waves/SIMD): per row i:
//   m = (b2 + (mean_j S) @ W2)/tau ; h = relu(m@Wa+ba);
//   y = h + x@Wr + br; out = LayerNorm(y)*gamma+beta.
// Grid 1024 x 128. Block = 1 i row, lane = 1 h column. Sums 8 Sp partials.
// ---------------------------------------------------------------------------
__global__ __launch_bounds__(128) void finish_kernel(
    const float* __restrict__ Sp, const float* __restrict__ W2,
    const float* __restrict__ b2, const float* __restrict__ x,
    const float* __restrict__ Wt, const float* __restrict__ bt,
    const float* __restrict__ Wa, const float* __restrict__ ba,
    const float* __restrict__ Wr, const float* __restrict__ br,
    const float* __restrict__ gamma, const float* __restrict__ beta,
    float* __restrict__ out)
{
    __shared__ float Srow[HH];
    __shared__ float mrow[HH];
    __shared__ float xrow[DD];
    __shared__ float red[2][2];
    __shared__ float tau_s;
    const int t = threadIdx.x;      // 0..127 = h column
    const int h = t;
    const int wv = t >> 6;          // 0..1
    const int l = t & 63;
    const int i = blockIdx.x;

    {
        float s = 0.f;
        #pragma unroll
        for (int q = 0; q < 8; q++)
            s += Sp[(q * BB + i) * HH + h];
        Srow[h] = s * (1.0f / (float)BB);
    }
    if (wv == 0) {
        float xv = x[i * DD + l];
        xrow[l] = xv;
        float p = xv * Wt[l];
        #pragma unroll
        for (int off = 32; off; off >>= 1) p += __shfl_xor(p, off, 64);
        if (l == 0) {
            float z = p + bt[0];
            float sp = (z > 20.f) ? z : log1pf(expf(z));
            tau_s = fmaxf(sp, 0.01f) + 1.0f;
        }
    }
    __syncthreads();

    float acc = b2[h];
    #pragma unroll 8
    for (int k = 0; k < HH; k++)
        acc = fmaf(Srow[k], W2[k * HH + h], acc);
    const float itau = 1.0f / tau_s;
    mrow[h] = acc * itau;
    __syncthreads();

    float a2 = ba[h];
    #pragma unroll 8
    for (int k = 0; k < HH; k++)
        a2 = fmaf(mrow[k], Wa[k * HH + h], a2);
    float y = fmaxf(a2, 0.f) + br[h];
    #pragma unroll 8
    for (int d = 0; d < DD; d++)
        y = fmaf(xrow[d], Wr[d * HH + h], y);

    // LayerNorm over 128 h (2 waves): shfl tree + LDS combine
    float p = y;
    #pragma unroll
    for (int off = 32; off; off >>= 1) p += __shfl_xor(p, off, 64);
    if (l == 0) red[0][wv] = p;
    __syncthreads();
    float mu = (red[0][0] + red[0][1]) * (1.0f / (float)HH);
    float dy = y - mu;
    float q = dy * dy;
    #pragma unroll
    for (int off = 32; off; off >>= 1) q += __shfl_xor(q, off, 64);
    if (l == 0) red[1][wv] = q;
    __syncthreads();
    float rs = rsqrtf((red[1][0] + red[1][1]) * (1.0f / (float)HH) + 1e-5f);
    out[i * HH + h] = dy * rs * gamma[h] + beta[h];
}

// ---------------------------------------------------------------------------
extern "C" void kernel_launch(void* const* d_in, const int* in_sizes, int n_in,
                              void* d_out, int out_size, void* d_ws, size_t ws_size,
                              hipStream_t stream)
{
    const float* x     = (const float*)d_in[0];
    const float* W1    = (const float*)d_in[1];
    const float* b1    = (const float*)d_in[2];
    const float* W2    = (const float*)d_in[3];
    const float* b2    = (const float*)d_in[4];
    const float* Wt    = (const float*)d_in[5];
    const float* bt    = (const float*)d_in[6];
    const float* Wa    = (const float*)d_in[7];
    const float* ba    = (const float*)d_in[8];
    const float* Wr    = (const float*)d_in[9];
    const float* br    = (const float*)d_in[10];
    const float* gamma = (const float*)d_in[11];
    const float* beta  = (const float*)d_in[12];
    float* out = (float*)d_out;

    char* ws = (char*)d_ws;
    float*     c1    = (float*)(ws);                         // 512 KB
    float*     c2P   = (float*)(ws + (512 << 10));           // 512 KB
    _Float16*  wpack = (_Float16*)(ws + (1024 << 10));       // 16 KB
    float*     Sp    = (float*)(ws + (1056 << 10));          // 4 MB (8 partials)

    prep_kernel<<<dim3(512, 2), 256, 0, stream>>>(x, W1, b1, c1, c2P, wpack);
    pair_kernel<<<2048, 256, 0, stream>>>(x, c1, c2P, wpack, Sp);
    finish_kernel<<<1024, 128, 0, stream>>>(Sp, W2, b2, x, Wt, bt,
                                            Wa, ba, Wr, br, gamma, beta, out);
}

// Round 10
// 124.444 us; speedup vs baseline: 1.0301x; 1.0301x over previous
//
#include <hip/hip_runtime.h>
#include <hip/hip_bf16.h>
#include <math.h>

#define BB 1024
#define DD 64
#define HH 128

typedef _Float16 half8 __attribute__((ext_vector_type(8)));
typedef __fp16 fp16x2 __attribute__((ext_vector_type(2)));
typedef float floatx4 __attribute__((ext_vector_type(4)));

union H8 { fp16x2 p[4]; half8 v; };

// async global -> LDS, 16B per lane. lds base must be wave-uniform; HW adds lane*16.
__device__ __forceinline__ void async_cp16(const float* g, float* lds_wave_base) {
    __builtin_amdgcn_global_load_lds(
        (const __attribute__((address_space(1))) unsigned int*)g,
        (__attribute__((address_space(3))) unsigned int*)lds_wave_base,
        16, 0, 0);
}

// ---------------------------------------------------------------------------
// Prep v3 (4 waves/SIMD, same arithmetic):
//  grid (512, 2) x 256. Block = 2 i rows x 128 h columns (1 h per lane).
//  y==0: c1[i,h] = x_i @ (Wi+Wd) + b1
//  y==1: c2P scatter of x_j @ (Wj-Wd), + wpack (blocks 0..31)
//  c2P[(j>>4)*2048 + (h>>6)*1024 + ((h>>4)&3)*256
//      + ((j&15)>>2)*64 + (h&15)*4 + (j&3)]
//  wpack[((hh*8 + t4*2 + s)*64 + l)*8 + jj]
//      = f16( Wab[s*32 + (l>>4)*8 + jj][hh*64 + t4*16 + (l&15)] )
// ---------------------------------------------------------------------------
__global__ __launch_bounds__(256) void prep_kernel(
    const float* __restrict__ x, const float* __restrict__ W1,
    const float* __restrict__ b1,
    float* __restrict__ c1, float* __restrict__ c2P,
    _Float16* __restrict__ wpack)
{
    __shared__ float xs[2][DD];
    const int t = threadIdx.x;        // 0..255
    const int i0 = blockIdx.x * 2;
    if (t < 128) xs[t >> 6][t & 63] = x[i0 * DD + t];
    __syncthreads();

    const int ii = t >> 7;            // 0..1
    const int h = t & 127;            // h column (coalesced across lanes)
    const int i = i0 + ii;

    if (blockIdx.y == 0) {
        float a1 = 0.f;
        #pragma unroll 8
        for (int k = 0; k < DD; k++) {
            float wi = W1[k * HH + h];
            float wd = W1[(2 * DD + k) * HH + h];
            a1 = fmaf(xs[ii][k], wi + wd, a1);
        }
        c1[i * HH + h] = a1 + b1[h];
    } else {
        float a2 = 0.f;
        #pragma unroll 8
        for (int k = 0; k < DD; k++) {
            float wj = W1[(DD + k) * HH + h];
            float wd = W1[(2 * DD + k) * HH + h];
            a2 = fmaf(xs[ii][k], wj - wd, a2);
        }
        // scatter into hh-split MFMA C-fragment order (single column h)
        c2P[(i >> 4) * 2048 + (h >> 6) * 1024 + ((h >> 4) & 3) * 256
            + ((i & 15) >> 2) * 64 + (h & 15) * 4 + (i & 3)] = a2;

        if (blockIdx.x < 32) {
            int f = blockIdx.x * 256 + t;        // 0..8191
            int jj = f & 7;
            int l  = (f >> 3) & 63;
            int u  = f >> 9;                     // hh*8 + t4*2 + s
            int s  = u & 1, t4 = (u >> 1) & 3, hh = u >> 3;
            int k  = s * 32 + ((l >> 4) << 3) + jj;
            int hcol = hh * 64 + t4 * 16 + (l & 15);
            wpack[f] = (_Float16)W1[(3 * DD + k) * HH + hcol];
        }
    }
}

// ---------------------------------------------------------------------------
// Pair kernel v8 (wide tiles): Sp[jg][i][hh*64+..] = sum_{j in EIGHTH jg}
//     relu(|x_i-x_j| @ Wab[:,h-half] + c1[i] + c2[j])
// Grid 2048 = 128 ig x 2 hh x 8 jg. Block = 4 waves x 2 i = 8 i rows.
// Change vs v7: R8/R9 showed pair pinned ~38-40us with IDENTICAL per-CU
// barrier-interval totals (1024x16 == 2048x8 == 16384). Diagnosis:
// interval-count-bound (each __syncthreads costs a fixed vmcnt-drain +
// wave-skew overhead >> the ~400cy of compute inside). Fix: 32-j tiles
// (two 16-j sub-tiles per barrier interval) -> 4 tiles/block, 8192
// intervals chip-wide (HALF). Per-CU MFMA/LDS/VALU totals unchanged.
// LDS 32 KB/block (5 blocks/CU cap). Sub-tile body is v7's verbatim.
// Kept: 2 i/wave, c2 register-held as shared MFMA C, part-major
// conflict-free xs, max-fold relu (+c1 hoisted, 32 j per S-reg).
// ---------------------------------------------------------------------------
__global__ __launch_bounds__(256, 3) void pair_kernel(
    const float* __restrict__ x, const float* __restrict__ c1,
    const float* __restrict__ c2P, const _Float16* __restrict__ wpack,
    float* __restrict__ Sp)
{
    __shared__ __align__(16) float xs[2][2048];   // 2 x 8 KB: [sub][part][lane][4]
    __shared__ __align__(16) float c2s[2][2048];  // 2 x 8 KB: [sub][frag order]

    const int t = threadIdx.x;
    const int wave = t >> 6;
    const int l = t & 63;
    const int quad = l >> 4, lm = l & 15;
    const int bid = blockIdx.x;
    const int ig = bid >> 4;         // 0..127 (8 i rows per block)
    const int hh = (bid >> 3) & 1;
    const int jg = bid & 7;          // j eighth (128 j)
    const int iA = ig * 8 + wave * 2;
    const int iB = iA + 1;
    const int j0base = jg * 128;
    // xs staging source: lane l of wave w supplies row (l&15),
    // k-chunk c = (l>>4)*2 + (w&1) + ((w>>1)<<3)   (4 floats at c*4)
    const int xoff = ((l >> 4) * 2 + (wave & 1) + ((wave >> 1) << 3)) << 2;

    // stage tile 0 (async): 32 j = two 16-j subs
    {
        const int j0 = j0base;
        async_cp16(x + (j0 + lm) * DD + xoff,        &xs[0][0] + wave * 256);
        async_cp16(x + (j0 + 16 + lm) * DD + xoff,   &xs[0][1024] + wave * 256);
        async_cp16(c2P + (j0 >> 4) * 2048 + hh * 1024 + t * 4,
                   &c2s[0][0] + wave * 256);
        async_cp16(c2P + ((j0 >> 4) + 1) * 2048 + hh * 1024 + t * 4,
                   &c2s[0][1024] + wave * 256);
    }

    // wave-private register data (overlaps staging)
    float xiA[16], xiB[16];
    {
        const float* xg = x + iA * DD + quad * 8;
        *(float4*)(xiA)      = *(const float4*)(xg);
        *(float4*)(xiA + 4)  = *(const float4*)(xg + 4);
        *(float4*)(xiA + 8)  = *(const float4*)(xg + 32);
        *(float4*)(xiA + 12) = *(const float4*)(xg + 36);
        const float* xh = x + iB * DD + quad * 8;
        *(float4*)(xiB)      = *(const float4*)(xh);
        *(float4*)(xiB + 4)  = *(const float4*)(xh + 4);
        *(float4*)(xiB + 8)  = *(const float4*)(xh + 32);
        *(float4*)(xiB + 12) = *(const float4*)(xh + 36);
    }
    float c1A[4], c1B[4];
    #pragma unroll
    for (int t4 = 0; t4 < 4; t4++) {
        c1A[t4] = c1[iA * HH + hh * 64 + t4 * 16 + lm];
        c1B[t4] = c1[iB * HH + hh * 64 + t4 * 16 + lm];
    }
    half8 wf[8];
    #pragma unroll
    for (int u = 0; u < 8; u++)
        wf[u] = *(const half8*)(wpack + ((hh * 8 + u) * 64 + l) * 8);

    float SA[4] = {0.f, 0.f, 0.f, 0.f};
    float SB[4] = {0.f, 0.f, 0.f, 0.f};

    for (int tile = 0; tile < 4; ++tile) {
        const int cur = tile & 1;
        __syncthreads();   // staged data for 'tile' landed; other buffer free

        if (tile < 3) {    // prefetch next 32-j tile (async, 4 loads)
            const int jn = j0base + (tile + 1) * 32;
            async_cp16(x + (jn + lm) * DD + xoff,      &xs[cur ^ 1][0] + wave * 256);
            async_cp16(x + (jn + 16 + lm) * DD + xoff, &xs[cur ^ 1][1024] + wave * 256);
            async_cp16(c2P + (jn >> 4) * 2048 + hh * 1024 + t * 4,
                       &c2s[cur ^ 1][0] + wave * 256);
            async_cp16(c2P + ((jn >> 4) + 1) * 2048 + hh * 1024 + t * 4,
                       &c2s[cur ^ 1][1024] + wave * 256);
        }

        #pragma unroll
        for (int sub = 0; sub < 2; ++sub) {
            // A data (h-independent): part-major, conflict-free linear reads
            const float* xb = &xs[cur][sub * 1024 + l * 4];
            float4 a0 = *(const float4*)(xb);
            float4 a1 = *(const float4*)(xb + 256);
            float4 a2 = *(const float4*)(xb + 512);
            float4 a3 = *(const float4*)(xb + 768);

            // c2 fragment: loaded ONCE, shared as MFMA C for both i
            floatx4 c2v[4];
            #pragma unroll
            for (int t4 = 0; t4 < 4; t4++)
                c2v[t4] = *(const floatx4*)(&c2s[cur][sub * 1024 + t4 * 256 + l * 4]);

            // build BOTH i's A-fragments while a0..a3 live (then freed)
            H8 afA0, afA1, afB0, afB1;
            afA0.p[0] = __builtin_amdgcn_cvt_pkrtz(fabsf(xiA[0] - a0.x),  fabsf(xiA[1] - a0.y));
            afA0.p[1] = __builtin_amdgcn_cvt_pkrtz(fabsf(xiA[2] - a0.z),  fabsf(xiA[3] - a0.w));
            afA0.p[2] = __builtin_amdgcn_cvt_pkrtz(fabsf(xiA[4] - a1.x),  fabsf(xiA[5] - a1.y));
            afA0.p[3] = __builtin_amdgcn_cvt_pkrtz(fabsf(xiA[6] - a1.z),  fabsf(xiA[7] - a1.w));
            afA1.p[0] = __builtin_amdgcn_cvt_pkrtz(fabsf(xiA[8] - a2.x),  fabsf(xiA[9] - a2.y));
            afA1.p[1] = __builtin_amdgcn_cvt_pkrtz(fabsf(xiA[10] - a2.z), fabsf(xiA[11] - a2.w));
            afA1.p[2] = __builtin_amdgcn_cvt_pkrtz(fabsf(xiA[12] - a3.x), fabsf(xiA[13] - a3.y));
            afA1.p[3] = __builtin_amdgcn_cvt_pkrtz(fabsf(xiA[14] - a3.z), fabsf(xiA[15] - a3.w));
            afB0.p[0] = __builtin_amdgcn_cvt_pkrtz(fabsf(xiB[0] - a0.x),  fabsf(xiB[1] - a0.y));
            afB0.p[1] = __builtin_amdgcn_cvt_pkrtz(fabsf(xiB[2] - a0.z),  fabsf(xiB[3] - a0.w));
            afB0.p[2] = __builtin_amdgcn_cvt_pkrtz(fabsf(xiB[4] - a1.x),  fabsf(xiB[5] - a1.y));
            afB0.p[3] = __builtin_amdgcn_cvt_pkrtz(fabsf(xiB[6] - a1.z),  fabsf(xiB[7] - a1.w));
            afB1.p[0] = __builtin_amdgcn_cvt_pkrtz(fabsf(xiB[8] - a2.x),  fabsf(xiB[9] - a2.y));
            afB1.p[1] = __builtin_amdgcn_cvt_pkrtz(fabsf(xiB[10] - a2.z), fabsf(xiB[11] - a2.w));
            afB1.p[2] = __builtin_amdgcn_cvt_pkrtz(fabsf(xiB[12] - a3.x), fabsf(xiB[13] - a3.y));
            afB1.p[3] = __builtin_amdgcn_cvt_pkrtz(fabsf(xiB[14] - a3.z), fabsf(xiB[15] - a3.w));

            // --- i = iA: C = c2v (kept live); relu via max(.., -c1) ---
            {
                floatx4 acc[4];
                #pragma unroll
                for (int t4 = 0; t4 < 4; t4++) {
                    acc[t4] = __builtin_amdgcn_mfma_f32_16x16x32_f16(afA0.v, wf[t4 * 2 + 0], c2v[t4], 0, 0, 0);
                    acc[t4] = __builtin_amdgcn_mfma_f32_16x16x32_f16(afA1.v, wf[t4 * 2 + 1], acc[t4], 0, 0, 0);
                }
                #pragma unroll
                for (int t4 = 0; t4 < 4; t4++) {
                    SA[t4] += fmaxf(acc[t4][0], -c1A[t4]);
                    SA[t4] += fmaxf(acc[t4][1], -c1A[t4]);
                    SA[t4] += fmaxf(acc[t4][2], -c1A[t4]);
                    SA[t4] += fmaxf(acc[t4][3], -c1A[t4]);
                }
            }
            // --- i = iB: SAME c2v registers as C (no LDS re-read) ---
            {
                floatx4 acc[4];
                #pragma unroll
                for (int t4 = 0; t4 < 4; t4++) {
                    acc[t4] = __builtin_amdgcn_mfma_f32_16x16x32_f16(afB0.v, wf[t4 * 2 + 0], c2v[t4], 0, 0, 0);
                    acc[t4] = __builtin_amdgcn_mfma_f32_16x16x32_f16(afB1.v, wf[t4 * 2 + 1], acc[t4], 0, 0, 0);
                }
                #pragma unroll
                for (int t4 = 0; t4 < 4; t4++) {
                    SB[t4] += fmaxf(acc[t4][0], -c1B[t4]);
                    SB[t4] += fmaxf(acc[t4][1], -c1B[t4]);
                    SB[t4] += fmaxf(acc[t4][2], -c1B[t4]);
                    SB[t4] += fmaxf(acc[t4][3], -c1B[t4]);
                }
            }
        }
    }

    // hoisted +c1 term: each S reg accumulated 32 j-rows (4 tiles x 2 subs x 4)
    #pragma unroll
    for (int t4 = 0; t4 < 4; t4++) {
        SA[t4] = fmaf(32.f, c1A[t4], SA[t4]);
        SB[t4] = fmaf(32.f, c1B[t4], SB[t4]);
    }
    // reduce across the 4 quads (same h = lm+16*t4, different j-rows)
    #pragma unroll
    for (int t4 = 0; t4 < 4; t4++) {
        SA[t4] += __shfl_xor(SA[t4], 16, 64);
        SA[t4] += __shfl_xor(SA[t4], 32, 64);
        SB[t4] += __shfl_xor(SB[t4], 16, 64);
        SB[t4] += __shfl_xor(SB[t4], 32, 64);
    }
    if (quad == 0) {
        #pragma unroll
        for (int t4 = 0; t4 < 4; t4++) {
            Sp[(jg * BB + iA) * HH + hh * 64 + t4 * 16 + lm] = SA[t4];
            Sp[(jg * BB + iB) * HH + hh * 64 + t4 * 16 + lm] = SB[t4];
        }
    }
}

// ---------------------------------------------------------------------------
// Finish v4 (2 waves/SIMD): per row i:
//   m = (b2 + (mean_j S) @ W2)/tau ; h = relu(m@Wa+ba);
//   y = h + x@Wr + br; out = LayerNorm(y)*gamma+beta.
// Grid 1024 x 128. Block = 1 i row, lane = 1 h column. Sums 8 Sp partials.
// ---------------------------------------------------------------------------
__global__ __launch_bounds__(128) void finish_kernel(
    const float* __restrict__ Sp, const float* __restrict__ W2,
    const float* __restrict__ b2, const float* __restrict__ x,
    const float* __restrict__ Wt, const float* __restrict__ bt,
    const float* __restrict__ Wa, const float* __restrict__ ba,
    const float* __restrict__ Wr, const float* __restrict__ br,
    const float* __restrict__ gamma, const float* __restrict__ beta,
    float* __restrict__ out)
{
    __shared__ float Srow[HH];
    __shared__ float mrow[HH];
    __shared__ float xrow[DD];
    __shared__ float red[2][2];
    __shared__ float tau_s;
    const int t = threadIdx.x;      // 0..127 = h column
    const int h = t;
    const int wv = t >> 6;          // 0..1
    const int l = t & 63;
    const int i = blockIdx.x;

    {
        float s = 0.f;
        #pragma unroll
        for (int q = 0; q < 8; q++)
            s += Sp[(q * BB + i) * HH + h];
        Srow[h] = s * (1.0f / (float)BB);
    }
    if (wv == 0) {
        float xv = x[i * DD + l];
        xrow[l] = xv;
        float p = xv * Wt[l];
        #pragma unroll
        for (int off = 32; off; off >>= 1) p += __shfl_xor(p, off, 64);
        if (l == 0) {
            float z = p + bt[0];
            float sp = (z > 20.f) ? z : log1pf(expf(z));
            tau_s = fmaxf(sp, 0.01f) + 1.0f;
        }
    }
    __syncthreads();

    float acc = b2[h];
    #pragma unroll 8
    for (int k = 0; k < HH; k++)
        acc = fmaf(Srow[k], W2[k * HH + h], acc);
    const float itau = 1.0f / tau_s;
    mrow[h] = acc * itau;
    __syncthreads();

    float a2 = ba[h];
    #pragma unroll 8
    for (int k = 0; k < HH; k++)
        a2 = fmaf(mrow[k], Wa[k * HH + h], a2);
    float y = fmaxf(a2, 0.f) + br[h];
    #pragma unroll 8
    for (int d = 0; d < DD; d++)
        y = fmaf(xrow[d], Wr[d * HH + h], y);

    // LayerNorm over 128 h (2 waves): shfl tree + LDS combine
    float p = y;
    #pragma unroll
    for (int off = 32; off; off >>= 1) p += __shfl_xor(p, off, 64);
    if (l == 0) red[0][wv] = p;
    __syncthreads();
    float mu = (red[0][0] + red[0][1]) * (1.0f / (float)HH);
    float dy = y - mu;
    float q = dy * dy;
    #pragma unroll
    for (int off = 32; off; off >>= 1) q += __shfl_xor(q, off, 64);
    if (l == 0) red[1][wv] = q;
    __syncthreads();
    float rs = rsqrtf((red[1][0] + red[1][1]) * (1.0f / (float)HH) + 1e-5f);
    out[i * HH + h] = dy * rs * gamma[h] + beta[h];
}

// ---------------------------------------------------------------------------
extern "C" void kernel_launch(void* const* d_in, const int* in_sizes, int n_in,
                              void* d_out, int out_size, void* d_ws, size_t ws_size,
                              hipStream_t stream)
{
    const float* x     = (const float*)d_in[0];
    const float* W1    = (const float*)d_in[1];
    const float* b1    = (const float*)d_in[2];
    const float* W2    = (const float*)d_in[3];
    const float* b2    = (const float*)d_in[4];
    const float* Wt    = (const float*)d_in[5];
    const float* bt    = (const float*)d_in[6];
    const float* Wa    = (const float*)d_in[7];
    const float* ba    = (const float*)d_in[8];
    const float* Wr    = (const float*)d_in[9];
    const float* br    = (const float*)d_in[10];
    const float* gamma = (const float*)d_in[11];
    const float* beta  = (const float*)d_in[12];
    float* out = (float*)d_out;

    char* ws = (char*)d_ws;
    float*     c1    = (float*)(ws);                         // 512 KB
    float*     c2P   = (float*)(ws + (512 << 10));           // 512 KB
    _Float16*  wpack = (_Float16*)(ws + (1024 << 10));       // 16 KB
    float*     Sp    = (float*)(ws + (1056 << 10));          // 4 MB (8 partials)

    prep_kernel<<<dim3(512, 2), 256, 0, stream>>>(x, W1, b1, c1, c2P, wpack);
    pair_kernel<<<2048, 256, 0, stream>>>(x, c1, c2P, wpack, Sp);
    finish_kernel<<<1024, 128, 0, stream>>>(Sp, W2, b2, x, Wt, bt,
                                            Wa, ba, Wr, br, gamma, beta, out);
}